// Round 9
// baseline (100.844 us; speedup 1.0000x reference)
//
#include <hip/hip_runtime.h>

// ExpertCompoundTracker: MoE load-EMA + pairwise co-activation histogram.
// Inputs: expert_indices [N,K] int32, expert_weights (UNUSED),
//         expert_load_ema [E] f32, expert_pair_coactivation [E,E] f32.
// Outputs concat: new_load_ema [64] then new_coact [4096], f32.
//
// R9 = R8 + compacted triangle slices: ws slice = 2080-int upper triangle
// (row lo at off(lo)=64*lo-lo*(lo-1)/2) + 64 rowsums = 2144 ints (8.6 KB),
// halving slice traffic again (4.25 -> 2.2 MB each way); finalize reads are
// unswizzled contiguous runs, 1024 threads (16 slice-groups) halve depth.
// Keeps: batched loads + sched_barrier pin (R5), plain stores / no ws
// pre-zero / no global atomics (R7), no fences (R6 proved per-block device
// fences catastrophic), rowsum==3*count EMA identity (R1).

#define N_TOKENS    2097152
#define NUM_EXPERTS 64
#define NCELLS      (NUM_EXPERTS * NUM_EXPERTS)  // 4096
#define NTRI        2080                          // 64*65/2 upper-triangle cells
#define NBLOCKS     256
#define NTHREADS    1024
#define STRIDE      (NBLOCKS * NTHREADS)         // 262144 threads -> 8 tokens each
#define SLICE       (NTRI + NUM_EXPERTS)         // 2144 ints per slice (16B-aligned)

__device__ __forceinline__ int tri_off(int lo) {      // start of row lo
    return lo * NUM_EXPERTS - (lo * (lo - 1)) / 2;
}

__device__ __forceinline__ void pair_add(int* s, int a, int b) {
    const int lo = min(a, b), hi = max(a, b);
    // bijective in-row swizzle: bank = (hi%32) ^ (lo&31) -> uniform
    atomicAdd(&s[(lo << 6) + (hi ^ (lo & 31))], 1);
}

__device__ __forceinline__ void token_add(int* s, int4 v) {
    pair_add(s, v.x, v.y);
    pair_add(s, v.x, v.z);
    pair_add(s, v.x, v.w);
    pair_add(s, v.y, v.z);
    pair_add(s, v.y, v.w);
    pair_add(s, v.z, v.w);
}

__global__ __launch_bounds__(NTHREADS) void coact_accum_kernel(
    const int* __restrict__ idx, int* __restrict__ ws)
{
    __shared__ int s_coact[NCELLS];   // 16 KB, swizzled upper-triangle cells
    __shared__ int s_row[NUM_EXPERTS];
    ((int4*)s_coact)[threadIdx.x] = make_int4(0, 0, 0, 0);
    if (threadIdx.x < NUM_EXPERTS) s_row[threadIdx.x] = 0;
    __syncthreads();

    const int tid = blockIdx.x * NTHREADS + threadIdx.x;
    const int4* __restrict__ idx4 = (const int4*)idx;

    // All 8 independent global_load_dwordx4 in flight, one vmcnt drain
    // (R3/R4: compiler re-serializes to save VGPRs if allowed).
    int4 v[8];
    #pragma unroll
    for (int i = 0; i < 8; ++i) v[i] = idx4[tid + i * STRIDE];
    __builtin_amdgcn_sched_barrier(0);

    #pragma unroll
    for (int i = 0; i < 8; ++i) token_add(s_coact, v[i]);

    __syncthreads();

    // Block-local rowsum_e = sum_{j>e} U[e][j] + 2*U[e][e] + sum_{j<e} U[j][e]
    // (== 3 * block-local count[e]; summed across slices in finalize).
    {
        const int e = threadIdx.x & 63;
        const int c = threadIdx.x >> 6;            // 16 chunks of 4 columns
        int p = 0;
        #pragma unroll
        for (int k = 0; k < 4; ++k) {
            const int j = c * 4 + k;
            int u;
            if (j >= e) {
                u = s_coact[(e << 6) + (j ^ (e & 31))];
                if (j == e) u <<= 1;               // diagonal counts twice
            } else {
                u = s_coact[(j << 6) + (e ^ (j & 31))];
            }
            p += u;
        }
        atomicAdd(&s_row[e], p);
    }
    __syncthreads();

    // Store compacted slice: threads 0..519 write the triangle (4 cells as
    // one int4), threads 520..535 write the 64 rowsums. Plain stores,
    // write-before-read => no ws pre-zero, no global atomics.
    int* slice = ws + blockIdx.x * SLICE;
    if (threadIdx.x < NTRI / 4) {
        const int c0 = threadIdx.x * 4;
        // find row of c0 (rows are >=1 long; c0..c0+3 may span rows)
        int lo = (int)(64.5f - sqrtf(64.5f * 64.5f - 2.0f * (float)c0));
        while (tri_off(lo + 1) <= c0) ++lo;
        while (tri_off(lo) > c0) --lo;
        int4 o;
        int t_lo = lo;
        #pragma unroll
        for (int k = 0; k < 4; ++k) {
            const int c = c0 + k;
            if (tri_off(t_lo + 1) <= c) ++t_lo;     // at most +1 per step (rows >=1)
            const int hi = t_lo + (c - tri_off(t_lo));
            const int val = s_coact[(t_lo << 6) + (hi ^ (t_lo & 31))];
            ((int*)&o)[k] = val;
        }
        ((int4*)slice)[threadIdx.x] = o;
    } else if (threadIdx.x < NTRI / 4 + NUM_EXPERTS / 4) {
        const int r = threadIdx.x - NTRI / 4;
        ((int4*)(slice + NTRI))[r] = ((const int4*)s_row)[r];
    }
}

__global__ __launch_bounds__(1024) void finalize_kernel(
    const int* __restrict__ ws,
    const float* __restrict__ ema_in,
    const float* __restrict__ coact_in,
    float* __restrict__ out)
{
    __shared__ int red[1024];
    __shared__ int rowf[NUM_EXPERTS];
    __shared__ int s_rowsum;
    const int b = blockIdx.x;       // expert / matrix row
    const int t = threadIdx.x;
    const int L = NUM_EXPERTS - b;  // row length (j = b..63)
    if (t == 0) s_rowsum = 0;

    // EMA partial: one slice-rowsum per thread for t < NBLOCKS.
    const int ema_part = (t < NBLOCKS) ? ws[t * SLICE + NTRI + b] : 0;

    // Reduce compacted row b over 256 slices: 16 lane-groups x 16 slices,
    // contiguous (unswizzled) runs of L ints per slice.
    const int g = t >> 6, lane = t & 63;
    const int row0 = tri_off(b);
    int acc = 0;
    if (lane < L) {
        #pragma unroll 8
        for (int s = g * 16; s < g * 16 + 16; ++s)
            acc += ws[s * SLICE + row0 + lane];
    }
    red[t] = acc;
    __syncthreads();                 // also orders s_rowsum init before atomics

    if (t < L) {
        int v = 0;
        #pragma unroll
        for (int gg = 0; gg < 16; ++gg) v += red[gg * 64 + t];
        rowf[t] = v;                 // rowf[j-b] = U[b][j], j = b + t
    }
    if (t < NBLOCKS) atomicAdd(&s_rowsum, ema_part);
    __syncthreads();

    // Write symmetric outputs: block b owns row b (j>=b) and column b (j>b).
    if (t < L) {
        const int j = b + t;
        if (t == 0) {
            out[NUM_EXPERTS + b * 65] = coact_in[b * 65] + 2.0f * (float)rowf[0];
        } else {
            const float d = (float)rowf[t];
            out[NUM_EXPERTS + b * 64 + j] = coact_in[b * 64 + j] + d;
            out[NUM_EXPERTS + j * 64 + b] = coact_in[j * 64 + b] + d;
        }
    }
    if (t == 0) {
        const int count = s_rowsum / 3;   // exact: rowsum == 3*count
        const float load = (float)count / (float)N_TOKENS;
        out[b] = ema_in[b] * 0.99f + load * 0.01f;
    }
}

extern "C" void kernel_launch(void* const* d_in, const int* in_sizes, int n_in,
                              void* d_out, int out_size, void* d_ws, size_t ws_size,
                              hipStream_t stream)
{
    const int*   idx      = (const int*)d_in[0];
    // d_in[1] = expert_weights: unused by the reference -> never read.
    const float* ema_in   = (const float*)d_in[2];
    const float* coact_in = (const float*)d_in[3];
    float*       out      = (float*)d_out;
    int*         ws       = (int*)d_ws;   // 256 slices x 2144 ints = 2.2 MB, write-before-read

    coact_accum_kernel<<<NBLOCKS, NTHREADS, 0, stream>>>(idx, ws);
    finalize_kernel<<<NUM_EXPERTS, 1024, 0, stream>>>(ws, ema_in, coact_in, out);
}